// Round 4
// baseline (63.741 us; speedup 1.0000x reference)
//
#include <hip/hip_runtime.h>
#include <stdint.h>

#define BB 8
#define NN 2048
#define CC 128
#define OO 128

typedef __attribute__((ext_vector_type(8))) short bf16x8;
typedef __attribute__((ext_vector_type(4))) float f32x4;
typedef __attribute__((ext_vector_type(4))) int i32x4;
typedef __attribute__((ext_vector_type(4))) unsigned short u16x4;
typedef unsigned int u32;
typedef unsigned short u16;

__device__ __forceinline__ u16 f2bf(float f) {
    union { float f; u32 u; } v; v.f = f;
    u32 r = v.u + 0x7FFFu + ((v.u >> 16) & 1u);
    return (u16)(r >> 16);
}

// async global->LDS 16B: LDS dest wave-uniform base + lane*16; swizzle lives
// in the per-lane global source address (m104/m173 rule).
__device__ __forceinline__ void gl_lds16(const u16* g, u16* l) {
    __builtin_amdgcn_global_load_lds(
        (__attribute__((address_space(1))) void*)(uintptr_t)g,
        (__attribute__((address_space(3))) void*)l, 16, 0, 0);
}

// ---------------------------------------------------------------------------
// Kernel 0: Wt[o][c] = bf16(W_lin[c][o]).  16 blocks x 256 thr (tiny).
// ---------------------------------------------------------------------------
__global__ __launch_bounds__(256) void wt_kernel(
    const float* __restrict__ W_lin, u16* __restrict__ Wt)
{
    __shared__ float ws2[8][132];
    const int t = threadIdx.x, o0 = blockIdx.x * 8;
    f32x4 v = *(const f32x4*)(W_lin + (t >> 1) * OO + o0 + (t & 1) * 4);
    #pragma unroll
    for (int e = 0; e < 4; ++e) ws2[(t & 1) * 4 + e][t >> 1] = v[e];
    __syncthreads();
    const int oo = t >> 5, c0 = (t & 31) * 4;
    f32x4 u = *(const f32x4*)&ws2[oo][c0];
    u16x4 h;
    #pragma unroll
    for (int e = 0; e < 4; ++e) h[e] = f2bf(u[e]);
    *(u16x4*)(Wt + (size_t)(o0 + oo) * CC + c0) = h;
}

// ---------------------------------------------------------------------------
// Kernel 1: precompute via MFMA, no LDS.
//   sj[b][n] = x·w1 + b_fc ; sk[b][n] = x·w2 (f32); Yt = bf16((x@W_lin)^T)
// ---------------------------------------------------------------------------
__global__ __launch_bounds__(256) void precompute_kernel(
    const float* __restrict__ x, const float* __restrict__ W_fc,
    const float* __restrict__ b_fc, const u16* __restrict__ Wt,
    float* __restrict__ sj, float* __restrict__ sk, u16* __restrict__ Yt)
{
    const int t = threadIdx.x, l = t & 63, w = t >> 6;
    const int sl = l & 15, g = l >> 4;
    const int b  = blockIdx.x >> 6;
    const int k0 = (blockIdx.x & 63) << 5;
    const int mt = w & 1, nb = (w >> 1) << 2;
    const int row = k0 + mt * 16 + sl;
    const float* xr = x + ((size_t)(b * NN + row) << 7);

    bf16x8 a[4];
    float p1 = 0.f, p2 = 0.f;
    #pragma unroll
    for (int ks = 0; ks < 4; ++ks) {
        f32x4 lo4 = *(const f32x4*)(xr + ks * 32 + g * 8);
        f32x4 hi4 = *(const f32x4*)(xr + ks * 32 + g * 8 + 4);
        f32x4 w1l = *(const f32x4*)(W_fc + ks * 32 + g * 8);
        f32x4 w1h = *(const f32x4*)(W_fc + ks * 32 + g * 8 + 4);
        f32x4 w2l = *(const f32x4*)(W_fc + CC + ks * 32 + g * 8);
        f32x4 w2h = *(const f32x4*)(W_fc + CC + ks * 32 + g * 8 + 4);
        bf16x8 av;
        #pragma unroll
        for (int e = 0; e < 4; ++e) {
            p1 += lo4[e] * w1l[e] + hi4[e] * w1h[e];
            p2 += lo4[e] * w2l[e] + hi4[e] * w2h[e];
            av[e]     = (short)f2bf(lo4[e]);
            av[e + 4] = (short)f2bf(hi4[e]);
        }
        a[ks] = av;
    }
    p1 += __shfl_xor(p1, 16); p1 += __shfl_xor(p1, 32);
    p2 += __shfl_xor(p2, 16); p2 += __shfl_xor(p2, 32);
    if (w < 2 && g == 0) {
        sj[b * NN + row] = p1 + b_fc[0];
        sk[b * NN + row] = p2;
    }

    f32x4 acc[4];
    #pragma unroll
    for (int i = 0; i < 4; ++i) acc[i] = (f32x4){0.f, 0.f, 0.f, 0.f};
    #pragma unroll
    for (int i = 0; i < 4; ++i) {
        const u16* wp = Wt + (size_t)((nb + i) * 16 + sl) * CC;
        #pragma unroll
        for (int ks = 0; ks < 4; ++ks) {
            bf16x8 bv = *(const bf16x8*)(wp + ks * 32 + g * 8);
            acc[i] = __builtin_amdgcn_mfma_f32_16x16x32_bf16(a[ks], bv, acc[i], 0, 0, 0);
        }
    }
    #pragma unroll
    for (int i = 0; i < 4; ++i) {
        const int o = (nb + i) * 16 + sl;
        u16x4 h;
        #pragma unroll
        for (int e = 0; e < 4; ++e) h[e] = f2bf(acc[i][e]);
        *(u16x4*)(Yt + (size_t)(b * OO + o) * NN + k0 + mt * 16 + g * 4) = h;
    }
}

// ---------------------------------------------------------------------------
// Kernel 2: main fused aggregation — 256-k window structure.
// Per window (2 k-tiles): wave loads its 8 adj rows with ONE dwordx4 each
// (1KB contiguous burst/instr); P-phase computes all 32 sigmoids/lane;
// lanes 0..31 hold tile-even, 32..63 tile-odd -> half-wave pbuf writes
// fenced by the existing barriers (pbuf stays 8KB). Static A/B register
// double-buffer (macro unroll-2, no rotation moves). vmcnt(17) uniform:
// at each wait, younger ops = stage(8) + loadwin(9).
// 512 blocks (b = bid&7 XCD-pinned), 256 thr, 2 blocks/CU (72.2 KB LDS).
// ---------------------------------------------------------------------------
__global__ __launch_bounds__(256, 2) void graphconv_main(
    const int* __restrict__ adj, const float* __restrict__ sj,
    const float* __restrict__ sk, const u16* __restrict__ Yt,
    const float* __restrict__ b_lin, float* __restrict__ out)
{
    __shared__ __align__(16) u16 ybuf[2][16384];  // 2 x (128 o x 16 chunks x 8)
    __shared__ __align__(16) u16 pbuf[4096];      // 32 j x 16 chunks x 8 (one tile)
    __shared__ float Sld[32];

    const int t  = threadIdx.x;
    const int l  = t & 63, w = t >> 6;
    const int sw = l & 15, kg = l >> 4;
    const int kc = (l & 31) >> 1, hh = l & 1, ph = l >> 5;
    const int b  = blockIdx.x & 7;
    const int j0 = (blockIdx.x >> 3) << 5;

    // adj row base for this wave (rows j0 + w*8 + r), lane offset l*4 ints
    const int* adjw = adj + ((size_t)b * NN + j0 + w * 8) * NN + l * 4;
    const float* skw = sk + b * NN + l * 4;

    float sjr[8];
    #pragma unroll
    for (int r = 0; r < 8; ++r) sjr[r] = sj[b * NN + j0 + w * 8 + r];

    // Y staging: linear LDS dest, inverse-swizzled per-lane global source
    u32 yoff[8];
    #pragma unroll
    for (int i = 0; i < 8; ++i) {
        int u  = (w * 8 + i) * 64 + l;
        int o  = u >> 4;
        int c  = (u & 15) ^ (o & 15);
        yoff[i] = (u32)(b * OO + o) * NN + c * 8;
    }

    f32x4 acc[2][2];
    #pragma unroll
    for (int js = 0; js < 2; ++js)
        #pragma unroll
        for (int os = 0; os < 2; ++os) acc[js][os] = (f32x4){0.f, 0.f, 0.f, 0.f};
    float psum[8];
    #pragma unroll
    for (int r = 0; r < 8; ++r) psum[r] = 0.f;

    // prologue: loadwin(0)->A, loadwin(1)->B, stage(tile0)->ybuf[0]
    i32x4 aA[8], aB[8]; f32x4 sA, sB;
    #pragma unroll
    for (int r = 0; r < 8; ++r) aA[r] = *(const i32x4*)(adjw + (size_t)r * NN);
    sA = *(const f32x4*)(skw);
    #pragma unroll
    for (int r = 0; r < 8; ++r) aB[r] = *(const i32x4*)(adjw + (size_t)r * NN + 256);
    sB = *(const f32x4*)(skw + 256);
    #pragma unroll
    for (int i = 0; i < 8; ++i)
        gl_lds16(Yt + yoff[i], &ybuf[0][(w * 8 + i) * 512]);

#define WINDOW_BODY(M_, AV, SKV)                                              \
    {                                                                         \
        const int m_  = (M_);                                                 \
        const int kt1 = 2 * m_ + 1;                                           \
        /* P-phase: 8 rows x 4 k each, full 256-k window */                   \
        u16x4 hv[8];                                                          \
        _Pragma("unroll")                                                     \
        for (int r = 0; r < 8; ++r) {                                         \
            i32x4 av = AV[r];                                                 \
            _Pragma("unroll")                                                 \
            for (int e = 0; e < 4; ++e) {                                     \
                float z  = sjr[r] + SKV[e];                                   \
                float sg = __builtin_amdgcn_rcpf(1.0f + __expf(-z));          \
                float pv = av[e] ? sg : 0.0f;                                 \
                psum[r] += pv;                                                \
                hv[r][e] = f2bf(pv);                                          \
            }                                                                 \
        }                                                                     \
        if (ph == 0) {                                                        \
            _Pragma("unroll")                                                 \
            for (int r = 0; r < 8; ++r) {                                     \
                int R = w * 8 + r;                                            \
                int u = R * 16 + (kc ^ (R & 15));                             \
                *(u16x4*)&pbuf[u * 8 + hh * 4] = hv[r];                       \
            }                                                                 \
        }                                                                     \
        /* stage odd tile of this window */                                   \
        _Pragma("unroll")                                                     \
        for (int i = 0; i < 8; ++i)                                           \
            gl_lds16(Yt + yoff[i] + (kt1 << 7), &ybuf[1][(w * 8 + i) * 512]); \
        /* prefetch window m+2 into the just-consumed regs */                 \
        {                                                                     \
            const int mm = (m_ + 2 > 7) ? 7 : m_ + 2;                         \
            _Pragma("unroll")                                                 \
            for (int r = 0; r < 8; ++r)                                       \
                AV[r] = *(const i32x4*)(adjw + (size_t)r * NN + mm * 256);    \
            SKV = *(const f32x4*)(skw + mm * 256);                            \
        }                                                                     \
        asm volatile("s_waitcnt vmcnt(17)" ::: "memory");                     \
        asm volatile("s_waitcnt lgkmcnt(0)" ::: "memory");                    \
        __builtin_amdgcn_s_barrier();                                         \
        asm volatile("" ::: "memory");                                        \
        MFMA_STEP(0)                                                          \
        asm volatile("" ::: "memory");                                        \
        __builtin_amdgcn_s_barrier();                                         \
        asm volatile("" ::: "memory");                                        \
        if (ph == 1) {                                                        \
            _Pragma("unroll")                                                 \
            for (int r = 0; r < 8; ++r) {                                     \
                int R = w * 8 + r;                                            \
                int u = R * 16 + (kc ^ (R & 15));                             \
                *(u16x4*)&pbuf[u * 8 + hh * 4] = hv[r];                       \
            }                                                                 \
        }                                                                     \
        /* stage next window's even tile */                                   \
        {                                                                     \
            const int tn = (2 * m_ + 2 > 15) ? 15 : 2 * m_ + 2;               \
            _Pragma("unroll")                                                 \
            for (int i = 0; i < 8; ++i)                                       \
                gl_lds16(Yt + yoff[i] + (tn << 7),                            \
                         &ybuf[0][(w * 8 + i) * 512]);                        \
        }                                                                     \
        asm volatile("s_waitcnt vmcnt(17)" ::: "memory");                     \
        asm volatile("s_waitcnt lgkmcnt(0)" ::: "memory");                    \
        __builtin_amdgcn_s_barrier();                                         \
        asm volatile("" ::: "memory");                                        \
        MFMA_STEP(1)                                                          \
        asm volatile("" ::: "memory");                                        \
        __builtin_amdgcn_s_barrier();                                         \
        asm volatile("" ::: "memory");                                        \
    }

#define MFMA_STEP(BUF)                                                        \
    _Pragma("unroll")                                                         \
    for (int kk = 0; kk < 4; ++kk) {                                          \
        const int c = kk * 4 + kg;                                            \
        bf16x8 af[2], bfr[2];                                                 \
        _Pragma("unroll")                                                     \
        for (int js = 0; js < 2; ++js)                                        \
            af[js] = *(const bf16x8*)&pbuf[((js * 16 + sw) * 16 + (c ^ sw)) * 8]; \
        _Pragma("unroll")                                                     \
        for (int os = 0; os < 2; ++os) {                                      \
            int o = w * 32 + os * 16 + sw;                                    \
            bfr[os] = *(const bf16x8*)&ybuf[BUF][(o * 16 + (c ^ sw)) * 8];    \
        }                                                                     \
        _Pragma("unroll")                                                     \
        for (int js = 0; js < 2; ++js)                                        \
            _Pragma("unroll")                                                 \
            for (int os = 0; os < 2; ++os)                                    \
                acc[js][os] = __builtin_amdgcn_mfma_f32_16x16x32_bf16(        \
                    af[js], bfr[os], acc[js][os], 0, 0, 0);                   \
    }

    for (int mi = 0; mi < 4; ++mi) {
        WINDOW_BODY(2 * mi,     aA, sA)
        WINDOW_BODY(2 * mi + 1, aB, sB)
    }
#undef WINDOW_BODY
#undef MFMA_STEP

    // rowsum: full 64-lane reduce per row
    #pragma unroll
    for (int r = 0; r < 8; ++r) {
        float s = psum[r];
        s += __shfl_xor(s, 1);  s += __shfl_xor(s, 2);  s += __shfl_xor(s, 4);
        s += __shfl_xor(s, 8);  s += __shfl_xor(s, 16); s += __shfl_xor(s, 32);
        if (l == 0) Sld[w * 8 + r] = s;
    }
    __syncthreads();   // also drains tail junk DMA before LDS reuse ends

    #pragma unroll
    for (int js = 0; js < 2; ++js) {
        float rinv[4];
        #pragma unroll
        for (int i = 0; i < 4; ++i) rinv[i] = 1.0f / Sld[js * 16 + kg * 4 + i];
        #pragma unroll
        for (int os = 0; os < 2; ++os) {
            const int col = w * 32 + os * 16 + sw;
            const float bl = b_lin[col];
            #pragma unroll
            for (int i = 0; i < 4; ++i) {
                size_t row = (size_t)(b * NN + j0 + js * 16 + kg * 4 + i);
                out[row * OO + col] = acc[js][os][i] * rinv[i] + bl;
            }
        }
    }
}

extern "C" void kernel_launch(void* const* d_in, const int* in_sizes, int n_in,
                              void* d_out, int out_size, void* d_ws, size_t ws_size,
                              hipStream_t stream) {
    const float* x     = (const float*)d_in[0];
    const int*   adj   = (const int*)d_in[1];
    const float* W_fc  = (const float*)d_in[2];
    const float* b_fc  = (const float*)d_in[3];
    const float* W_lin = (const float*)d_in[4];
    const float* b_lin = (const float*)d_in[5];
    float* out = (float*)d_out;

    // workspace: Yt (bf16, 4MB) | sj (64KB) | sk (64KB) | Wt (32KB)
    u16*   Yt = (u16*)d_ws;
    float* sj = (float*)((char*)d_ws + (size_t)BB * OO * NN * sizeof(u16));
    float* sk = sj + BB * NN;
    u16*   Wt = (u16*)(sk + BB * NN);

    wt_kernel<<<16, 256, 0, stream>>>(W_lin, Wt);
    precompute_kernel<<<512, 256, 0, stream>>>(x, W_fc, b_fc, Wt, sj, sk, Yt);
    graphconv_main<<<512, 256, 0, stream>>>(adj, sj, sk, Yt, b_lin, out);
}